// Round 6
// baseline (272.811 us; speedup 1.0000x reference)
//
#include <hip/hip_runtime.h>
#include <hip/hip_bf16.h>

typedef float f32x4 __attribute__((ext_vector_type(4)));
typedef __bf16 bf16x8 __attribute__((ext_vector_type(8)));
typedef unsigned int u32;
typedef unsigned int u32x2 __attribute__((ext_vector_type(2)));
typedef unsigned int u32x4 __attribute__((ext_vector_type(4)));
typedef unsigned short u16;

#define NH 8
#define HD 128
#define ROWE 1024        // fp32 elems per token row (H*D)
#define JB 32            // keys per j-tile
#define VSTR2 72         // prep LDS transpose stride (16B-aligned rows)

static __device__ __forceinline__ u16 bfb(float f) {
  return __builtin_bit_cast(u16, __float2bfloat16(f));
}
static __device__ __forceinline__ u32 pk2(float lo, float hi) {
  return (u32)bfb(lo) | ((u32)bfb(hi) << 16);
}

union FR { u32 u[4]; u32x4 q; bf16x8 v; };

// ---------------- prep: K -> bf16 [h][tok][d]; V -> bf16 transposed [h][dv][tok] ----------------
__global__ __launch_bounds__(256) void prep_cvt(
    const float* __restrict__ tk, const float* __restrict__ tv,
    u16* __restrict__ kb, u16* __restrict__ vt, int nrows)
{
  __shared__ __align__(16) u16 vlds[HD * VSTR2];   // 18.4 KB

  const int h = blockIdx.x & 7;
  const int tok0 = (blockIdx.x >> 3) * 64;
  const int tid = threadIdx.x;
  const int cap = nrows - 1;

  u16* kbh = kb + (size_t)h * nrows * HD;
  u16* vth = vt + (size_t)h * HD * nrows;

  // pass 1: 8 units/thread; unit u -> (tok=u>>5, c=u&31): K copy-cvt + V cvt into LDS^T
#pragma unroll
  for (int it = 0; it < 8; ++it) {
    int u = tid + it * 256;
    int tok = u >> 5, c = u & 31;
    int row = tok0 + tok; if (row > cap) row = cap;
    size_t g = (size_t)row * ROWE + h * HD + 4 * c;
    f32x4 kv = *(const f32x4*)(tk + g);
    f32x4 vv = *(const f32x4*)(tv + g);
    u32x2 kp; kp.x = pk2(kv.x, kv.y); kp.y = pk2(kv.z, kv.w);
    if (tok0 + tok <= cap)
      *(u32x2*)(kbh + (size_t)(tok0 + tok) * HD + 4 * c) = kp;
    vlds[(4 * c + 0) * VSTR2 + tok] = bfb(vv.x);
    vlds[(4 * c + 1) * VSTR2 + tok] = bfb(vv.y);
    vlds[(4 * c + 2) * VSTR2 + tok] = bfb(vv.z);
    vlds[(4 * c + 3) * VSTR2 + tok] = bfb(vv.w);
  }
  __syncthreads();
  // pass 2: 4 units/thread; unit u -> (dv=u>>3, tch=u&7): b128 LDS row -> global V^T
#pragma unroll
  for (int it = 0; it < 4; ++it) {
    int u = tid + it * 256;
    int dv = u >> 3, tch = u & 7;
    u32x4 row = *(const u32x4*)(&vlds[dv * VSTR2 + tch * 8]);
    int t0 = tok0 + tch * 8;
    if (t0 + 7 <= cap)
      *(u32x4*)(vth + (size_t)dv * nrows + t0) = row;
    else {
      const u16* s = (const u16*)&row;
      for (int i = 0; i < 8 && t0 + i <= cap; ++i) vth[(size_t)dv * nrows + t0 + i] = s[i];
    }
  }
}

// ---------------- main: one independent WAVE per (head, 16-row q-strip); no LDS, no barriers ----------------
__global__ __launch_bounds__(256, 3) void hstu_fwd(
    const u16* __restrict__ kb, const u16* __restrict__ vt,
    const float* __restrict__ tq, const int* __restrict__ offs,
    const int* __restrict__ pms, const int* __restrict__ pss,
    float* __restrict__ out, int nrows)
{
  const int h = blockIdx.x & 7;          // head pinned -> XCD L2 locality
  const int r = blockIdx.x >> 3;
  const int tid = threadIdx.x;
  const int lane = tid & 63;
  const int w = tid >> 6;
  const int lrow = lane & 15;
  const int lgrp = lane >> 4;

  int o[9];
#pragma unroll
  for (int i = 0; i < 9; ++i) o[i] = offs[i];

  // sorted-strip lookup: this wave takes the (r*4+w)-th strip in DESCENDING-length order
  int want = r * 4 + w, selk = -1, soff = 0, sn = 0;
  for (int k = 63; k >= 0; --k) {
    for (int b = 0; b < 8; ++b) {
      int n = o[b + 1] - o[b];
      if (k * 16 < n) {
        if (want == 0 && selk < 0) { selk = k; soff = o[b]; sn = n; }
        --want;
      }
    }
  }
  if (selk < 0) return;

  const float qscale = 0.12751744f;      // (1/sqrt(128)) * log2(e)
  int ms = pms[0], ss = pss[0];
  float den = (ss > 0) ? (float)ss : (float)ms;
  const float cs = 0.69314718056f / den; // ln2 / denom

  const int q0 = selk * 16;
  const int iq = q0 + lrow;              // this lane's query row

  // ---- Q fragments: contiguous k-chunks d = ds*32 + lgrp*8 + i, pre-scaled ----
  FR qf[4];
  {
    const float* qp = tq + (size_t)(soff + q0 + lrow) * ROWE + h * HD;
#pragma unroll
    for (int ds = 0; ds < 4; ++ds) {
      f32x4 a = *(const f32x4*)(qp + ds * 32 + lgrp * 8);
      f32x4 b = *(const f32x4*)(qp + ds * 32 + lgrp * 8 + 4);
      qf[ds].u[0] = pk2(a.x * qscale, a.y * qscale);
      qf[ds].u[1] = pk2(a.z * qscale, a.w * qscale);
      qf[ds].u[2] = pk2(b.x * qscale, b.y * qscale);
      qf[ds].u[3] = pk2(b.z * qscale, b.w * qscale);
    }
  }

  const u16* kbh = kb + (size_t)h * nrows * HD;
  const u16* vth = vt + (size_t)h * HD * nrows;

  f32x4 acc[8];
#pragma unroll
  for (int i = 0; i < 8; ++i) acc[i] = (f32x4){0.f, 0.f, 0.f, 0.f};

  const int ntj = (selk >> 1) + 1;       // j-tiles with j0 <= q0+15

  for (int tt = 0; tt < ntj; ++tt) {
    const int j0 = tt * JB;

    // ---- K fragments: one b128 per (ds, half): rows j0+lrow / j0+16+lrow ----
    const u16* k0p = kbh + (size_t)(soff + j0 + lrow) * HD + lgrp * 8;
    const u16* k1p = k0p + 16 * HD;
    FR a0[4], a1[4];
#pragma unroll
    for (int ds = 0; ds < 4; ++ds) {
      a0[ds].q = *(const u32x4*)(k0p + ds * 32);
      a1[ds].q = *(const u32x4*)(k1p + ds * 32);
    }
    // ---- V fragments (round-2-verified j-map): j = j0 + 4*lgrp + {0..3} and +16 ----
    FR vf[8];
#pragma unroll
    for (int sd = 0; sd < 8; ++sd) {
      const u16* vp = vth + (size_t)(sd * 16 + lrow) * nrows + soff + j0 + 4 * lgrp;
      *(u32x2*)(&vf[sd].u[0]) = *(const u32x2*)(vp);
      *(u32x2*)(&vf[sd].u[2]) = *(const u32x2*)(vp + 16);
    }

    // ---- S^T = K . Q^T (swapped so P lands lane-local for PV) ----
    f32x4 s0 = {0.f, 0.f, 0.f, 0.f}, s1 = {0.f, 0.f, 0.f, 0.f};
#pragma unroll
    for (int ds = 0; ds < 4; ++ds) {
      s0 = __builtin_amdgcn_mfma_f32_16x16x32_bf16(a0[ds].v, qf[ds].v, s0, 0, 0, 0);
      s1 = __builtin_amdgcn_mfma_f32_16x16x32_bf16(a1[ds].v, qf[ds].v, s1, 0, 0, 0);
    }

    // ---- silu + causal mask + pack P (bf16) ----
    const int jb0 = j0 + 4 * lgrp;
    float pv[8];
#pragma unroll
    for (int rr = 0; rr < 4; ++rr) {
      float y0 = s0[rr], y1 = s1[rr];                // y = x*log2e
      float z0 = __fdividef(y0, 1.f + exp2f(-y0));
      float z1 = __fdividef(y1, 1.f + exp2f(-y1));
      pv[rr]     = (jb0 + rr      <= iq) ? z0 : 0.f;
      pv[rr + 4] = (jb0 + 16 + rr <= iq) ? z1 : 0.f;
    }
    FR pf;
    pf.u[0] = pk2(pv[0], pv[1]); pf.u[1] = pk2(pv[2], pv[3]);
    pf.u[2] = pk2(pv[4], pv[5]); pf.u[3] = pk2(pv[6], pv[7]);

    // ---- out += P . V ----
#pragma unroll
    for (int sd = 0; sd < 8; ++sd)
      acc[sd] = __builtin_amdgcn_mfma_f32_16x16x32_bf16(pf.v, vf[sd].v, acc[sd], 0, 0, 0);
  }

  // ---- epilogue: scale, direct store (sole writer of this strip) ----
#pragma unroll
  for (int rr = 0; rr < 4; ++rr) {
    int ir = q0 + 4 * lgrp + rr;
    float* op = out + (size_t)(soff + ir) * ROWE + h * HD + lrow;
#pragma unroll
    for (int sd = 0; sd < 8; ++sd) op[sd * 16] = acc[sd][rr] * cs;
  }
}

extern "C" void kernel_launch(void* const* d_in, const int* in_sizes, int n_in,
                              void* d_out, int out_size, void* d_ws, size_t ws_size,
                              hipStream_t stream) {
  const float* tq = (const float*)d_in[0];
  const float* tk = (const float*)d_in[1];
  const float* tv = (const float*)d_in[2];
  const int* offs = (const int*)d_in[3];
  const int* pms  = (const int*)d_in[4];
  const int* pss  = (const int*)d_in[5];
  float* out = (float*)d_out;

  int nrows = in_sizes[0] / ROWE;
  u16* kbw = (u16*)d_ws;                       // bf16 K [h][tok][d]
  u16* vbt = kbw + (size_t)nrows * ROWE;       // bf16 V^T [h][dv][tok]

  int tokblks = (nrows + 63) / 64;
  hipLaunchKernelGGL(prep_cvt, dim3(NH * tokblks), dim3(256), 0, stream,
                     tk, tv, kbw, vbt, nrows);

  int nstrips = 0;                             // host doesn't know offsets; size by upper bound
  nstrips = nrows / 16 + 8;                    // >= true strip count
  int blocks = (nstrips + 3) / 4;
  hipLaunchKernelGGL(hstu_fwd, dim3(NH * blocks), dim3(256), 0, stream,
                     kbw, vbt, tq, offs, pms, pss, out, nrows);
}

// Round 7
// 145.378 us; speedup vs baseline: 1.8766x; 1.8766x over previous
//
#include <hip/hip_runtime.h>
#include <hip/hip_bf16.h>

typedef float f32x4 __attribute__((ext_vector_type(4)));
typedef __bf16 bf16x8 __attribute__((ext_vector_type(8)));
typedef unsigned int u32;
typedef unsigned int u32x2 __attribute__((ext_vector_type(2)));
typedef unsigned short u16;

#define NH 8
#define HD 128
#define ROWE (NH*HD)     // 1024 floats per token row
#define QB 64            // q rows per block
#define JB 32            // keys per j-tile
#define KSTR 148         // K LDS row stride (bf16 elems) — round-2 verified
#define VSTR 36          // V^T LDS row stride (bf16 elems) — round-2 verified
#define KSZ (JB*KSTR)    // 4736 elems per K tile-slot
#define VSZ (HD*VSTR)    // 4608 elems per V tile-slot

__device__ __forceinline__ u16 bfb(float f) {
  return __builtin_bit_cast(u16, __float2bfloat16(f));
}
__device__ __forceinline__ u32 pk2(float lo, float hi) {
  return (u32)bfb(lo) | ((u32)bfb(hi) << 16);
}

union FR { u32 u[4]; bf16x8 v; };

struct StReg { f32x4 k[4]; f32x4 v[4]; };

// unit -> (float4-col c in 0..31, row j in 0..31) — round-2 verified mapping
__device__ __forceinline__ void unit_cj(int u, int& c, int& j) {
  c = (u & 3) | (((u >> 4) & 7) << 2);
  j = ((u >> 2) & 3) | (((u >> 7) & 7) << 2);
}

__device__ __forceinline__ void stage_load(StReg& s, const float* __restrict__ tk,
    const float* __restrict__ tv, int base_row, int cap, int hoff, int tidL) {
#pragma unroll
  for (int it = 0; it < 4; ++it) {
    int c, j; unit_cj(tidL + (it << 8), c, j);
    int row = base_row + j; if (row > cap) row = cap;
    size_t g = (size_t)row * ROWE + hoff + 4*c;
    s.k[it] = *(const f32x4*)(tk + g);
    s.v[it] = *(const f32x4*)(tv + g);
  }
}

__device__ __forceinline__ void stage_write(const StReg& s, u16* kw, u16* vw, int tidL) {
#pragma unroll
  for (int it = 0; it < 4; ++it) {
    int c, j; unit_cj(tidL + (it << 8), c, j);
    u32x2 kp; kp.x = pk2(s.k[it].x, s.k[it].y); kp.y = pk2(s.k[it].z, s.k[it].w);
    *(u32x2*)(&kw[j*KSTR + 4*c]) = kp;          // K row-major [j][d]
    vw[(4*c+0)*VSTR + j] = bfb(s.v[it].x);      // V transposed [dv][j]
    vw[(4*c+1)*VSTR + j] = bfb(s.v[it].y);
    vw[(4*c+2)*VSTR + j] = bfb(s.v[it].z);
    vw[(4*c+3)*VSTR + j] = bfb(s.v[it].w);
  }
}

__global__ __launch_bounds__(512, 4) void hstu_fwd(
    const float* __restrict__ tq, const float* __restrict__ tk,
    const float* __restrict__ tv, const int* __restrict__ offs,
    const int* __restrict__ pms, const int* __restrict__ pss,
    float* __restrict__ out, int nrows)
{
  __shared__ __align__(16) u16 kbuf[4][KSZ];   // 4-slot tile ring
  __shared__ __align__(16) u16 vbuf[4][VSZ];   // total 74.75 KB -> 2 blocks/CU

  const int h = blockIdx.x & 7;          // head -> same XCD for all its blocks
  int r = blockIdx.x >> 3;

  int o[9];
#pragma unroll
  for (int i = 0; i < 9; ++i) o[i] = offs[i];

  // map r -> (seq b, q-tile) in DESCENDING q-tile order (largest work first)
  int selq = -1, soff = 0, sn = 0;
  for (int k = 15; k >= 0; --k) {
#pragma unroll
    for (int b = 0; b < 8; ++b) {
      int nseq = o[b+1] - o[b];
      int ntb = (nseq + 63) >> 6;
      if (k < ntb) {
        if (r == 0 && selq < 0) { selq = k; soff = o[b]; sn = nseq; }
        --r;
      }
    }
  }
  if (selq < 0) return;                  // spare block (block-uniform exit)

  const int cap  = nrows - 1;
  const int q0   = selq * QB;
  const int tid  = threadIdx.x;
  const int tidL = tid & 255;            // staging lane-id within tile-half
  const int lane = tid & 63;
  const int w    = tid >> 6;             // 8 waves
  const int s    = w & 3;                // q-strip: rows [q0+16s, q0+16s+16)
  const int th   = w >> 2;               // j-parity: this wave does tiles t%2==th
  const int lrow = lane & 15;
  const int lgrp = lane >> 4;
  const int hoff = h * HD;

  const float qscale = 0.12751744f;      // (1/sqrt(128)) * log2(e)
  int ms = pms[0], ss = pss[0];
  float den = (ss > 0) ? (float)ss : (float)ms;
  const float cs = 0.69314718056f / den; // ln2 / denom, folded into epilogue

  // ---- Q fragments (B operand of S^T mfma), pre-scaled ----
  FR qf[4];
  {
    int qrow = soff + q0 + 16*s + lrow; if (qrow > cap) qrow = cap;
    const float* qp = tq + (size_t)qrow * ROWE + hoff;
#pragma unroll
    for (int ds = 0; ds < 4; ++ds) {
      f32x4 a = *(const f32x4*)(qp + ds*32 + 4*lgrp);
      f32x4 b = *(const f32x4*)(qp + ds*32 + 4*lgrp + 16);
      qf[ds].u[0] = pk2(a.x*qscale, a.y*qscale);
      qf[ds].u[1] = pk2(a.z*qscale, a.w*qscale);
      qf[ds].u[2] = pk2(b.x*qscale, b.y*qscale);
      qf[ds].u[3] = pk2(b.z*qscale, b.w*qscale);
    }
  }

  f32x4 acc[8];
#pragma unroll
  for (int i = 0; i < 8; ++i) acc[i] = (f32x4){0.f, 0.f, 0.f, 0.f};

  int jend = q0 + QB; if (jend > sn) jend = sn;
  const int ntj = (jend + JB - 1) >> 5;
  const int iq  = q0 + 16*s + lrow;      // this lane's query index

  // compute one 32-key tile from ring slot (t&3) — body byte-identical to round 2
  auto compute = [&](int t) {
    const int j0 = t * JB;
    if (q0 + 16*s + 15 < j0) return;     // wave fully above diagonal: skip
    const int sl = t & 3;
    const char* kbc = (const char*)kbuf[sl] + lrow*(2*KSTR) + lgrp*8;
    f32x4 s0 = {0,0,0,0}, s1 = {0,0,0,0};
#pragma unroll
    for (int ds = 0; ds < 4; ++ds) {
      FR a0, a1;
      const char* p = kbc + ds*64;
      *(u32x2*)(&a0.u[0]) = *(const u32x2*)(p);
      *(u32x2*)(&a0.u[2]) = *(const u32x2*)(p + 32);
      *(u32x2*)(&a1.u[0]) = *(const u32x2*)(p + 16*2*KSTR);
      *(u32x2*)(&a1.u[2]) = *(const u32x2*)(p + 16*2*KSTR + 32);
      s0 = __builtin_amdgcn_mfma_f32_16x16x32_bf16(a0.v, qf[ds].v, s0, 0, 0, 0);
      s1 = __builtin_amdgcn_mfma_f32_16x16x32_bf16(a1.v, qf[ds].v, s1, 0, 0, 0);
    }
    const int jb0 = j0 + 4*lgrp;
    float pv[8];
#pragma unroll
    for (int rr = 0; rr < 4; ++rr) {
      float y0 = s0[rr], y1 = s1[rr];              // y = x*log2e
      float z0 = __fdividef(y0, 1.f + exp2f(-y0));
      float z1 = __fdividef(y1, 1.f + exp2f(-y1));
      pv[rr]   = (jb0 + rr      <= iq) ? z0 : 0.f;
      pv[rr+4] = (jb0 + 16 + rr <= iq) ? z1 : 0.f;
    }
    FR pf;
    pf.u[0] = pk2(pv[0], pv[1]); pf.u[1] = pk2(pv[2], pv[3]);
    pf.u[2] = pk2(pv[4], pv[5]); pf.u[3] = pk2(pv[6], pv[7]);
    const char* vbc = (const char*)vbuf[sl] + lrow*(2*VSTR) + lgrp*8;
#pragma unroll
    for (int sd = 0; sd < 8; ++sd) {
      FR vf;
      const char* p2 = vbc + sd*(16*2*VSTR);
      *(u32x2*)(&vf.u[0]) = *(const u32x2*)(p2);
      *(u32x2*)(&vf.u[2]) = *(const u32x2*)(p2 + 32);
      acc[sd] = __builtin_amdgcn_mfma_f32_16x16x32_bf16(pf.v, vf.v, acc[sd], 0, 0, 0);
    }
  };

  // ---- prologue: tile th -> slot th ----
  StReg st;
  if (th < ntj) {
    stage_load(st, tk, tv, soff + th*JB, cap, hoff, tidL);
    stage_write(st, kbuf[th], vbuf[th], tidL);
  }

  // ---- main: each interval computes tiles {2u, 2u+1}, stages {2u+2, 2u+3} ----
  const int U = (ntj + 1) >> 1;
  for (int u = 0; u < U; ++u) {
    __syncthreads();
    const int tl = 2*u + 2 + th;
    if (tl < ntj) stage_load(st, tk, tv, soff + tl*JB, cap, hoff, tidL);
    const int tc = 2*u + th;
    if (tc < ntj) compute(tc);
    if (tl < ntj) stage_write(st, kbuf[tl & 3], vbuf[tl & 3], tidL);
  }

  // ---- cross-parity reduction (th=1 partials -> th=0) via LDS, then store ----
  __syncthreads();
  float* red = (float*)kbuf;             // 4*64*32 floats = 32 KB, fits kbuf
  if (th == 1) {
    float* rp = red + ((s * 64 + lane) << 5);
#pragma unroll
    for (int i = 0; i < 8; ++i) *(f32x4*)(rp + 4*i) = acc[i];
  }
  __syncthreads();
  if (th == 0) {
    const float* rp = red + ((s * 64 + lane) << 5);
#pragma unroll
    for (int i = 0; i < 8; ++i) acc[i] += *(const f32x4*)(rp + 4*i);
    const int or0 = q0 + 16*s + 4*lgrp;
#pragma unroll
    for (int rr = 0; rr < 4; ++rr) {
      int ir = or0 + rr;
      if (ir < sn) {
        float* op = out + (size_t)(soff + ir) * ROWE + hoff + lrow;
#pragma unroll
        for (int sd = 0; sd < 8; ++sd) op[sd*16] = acc[sd][rr] * cs;
      }
    }
  }
}

extern "C" void kernel_launch(void* const* d_in, const int* in_sizes, int n_in,
                              void* d_out, int out_size, void* d_ws, size_t ws_size,
                              hipStream_t stream) {
  const float* tq = (const float*)d_in[0];
  const float* tk = (const float*)d_in[1];
  const float* tv = (const float*)d_in[2];
  const int* offs = (const int*)d_in[3];
  const int* pms  = (const int*)d_in[4];
  const int* pss  = (const int*)d_in[5];
  float* out = (float*)d_out;

  int nrows = in_sizes[0] / ROWE;            // total jagged tokens
  int nb    = in_sizes[3] - 1;               // B
  int maxtiles = nrows / QB + nb;            // upper bound on q-tiles
  dim3 grid(NH * maxtiles);
  hipLaunchKernelGGL(hstu_fwd, grid, dim3(512), 0, stream,
                     tq, tk, tv, offs, pms, pss, out, nrows);
}